// Round 1
// baseline (4574.385 us; speedup 1.0000x reference)
//
#include <hip/hip_runtime.h>
#include <hip/hip_bf16.h>
#include <stdint.h>

#define LATENT 64
#define CONDD  96
#define NEUR   128
#define DIN0   160   // LATENT + CONDD
#define NSEQ   512
#define ROWS   4     // batch rows per block
#define SP0    168   // LDS row stride (elems) for w0t: mult of 8, bank-spread
#define SP1    136   // LDS row stride for w1t/w2t/wot

__device__ __forceinline__ float lo16(uint32_t u){ return __uint_as_float(u << 16); }
__device__ __forceinline__ float hi16(uint32_t u){ return __uint_as_float(u & 0xFFFF0000u); }
__device__ __forceinline__ unsigned short f2bf(float f){
  uint32_t u = __float_as_uint(f);
  u += 0x7FFFu + ((u >> 16) & 1u);   // round-to-nearest-even
  return (unsigned short)(u >> 16);
}
__device__ __forceinline__ float tanh_fast(float v){
  // 1 - 2/(e^{2v}+1): saturates correctly for |v| large (inf -> 1, 0 -> -1)
  float e = __expf(2.f * v);
  return 1.f - __fdividef(2.f, e + 1.f);
}

// One hidden layer: h = tanh(LN(x @ W + b) * g + beta), for 4 rows.
// Thread t: neuron j = t&127, handles rows {2*(t>>7), 2*(t>>7)+1}.
template<int KLEN>
__device__ __forceinline__ void layer_fwd(
    const unsigned short* __restrict__ wt, const int wstride,
    const float* __restrict__ xbuf, const int xstride,
    float* __restrict__ hraw, float* __restrict__ hact,
    const float* __restrict__ bias, const float* __restrict__ gain,
    const float* __restrict__ beta,
    float* __restrict__ mu_s, float* __restrict__ rs_s, const int t)
{
  const int j = t & (NEUR - 1);
  const int p2 = t >> 7;
  const int rowA = p2 << 1, rowB = rowA | 1;
  const int wrow = t >> 6, lane = t & 63;

  float a0 = 0.f, a1 = 0.f, c0 = 0.f, c1 = 0.f;
  const unsigned short* wr = wt + j * wstride;
  const float* xA = xbuf + rowA * xstride;
  const float* xB = xbuf + rowB * xstride;
#pragma unroll 4
  for (int k = 0; k < KLEN; k += 8) {
    const uint4 wq = *(const uint4*)(wr + k);           // 8 bf16 weights
    const float4 xa0 = *(const float4*)(xA + k);
    const float4 xa1 = *(const float4*)(xA + k + 4);
    const float4 xb0 = *(const float4*)(xB + k);
    const float4 xb1 = *(const float4*)(xB + k + 4);
    const float w0 = lo16(wq.x), w1 = hi16(wq.x), w2 = lo16(wq.y), w3 = hi16(wq.y);
    const float w4 = lo16(wq.z), w5 = hi16(wq.z), w6 = lo16(wq.w), w7 = hi16(wq.w);
    a0 = fmaf(xa0.x, w0, a0); c0 = fmaf(xa0.y, w1, c0);
    a0 = fmaf(xa0.z, w2, a0); c0 = fmaf(xa0.w, w3, c0);
    a0 = fmaf(xa1.x, w4, a0); c0 = fmaf(xa1.y, w5, c0);
    a0 = fmaf(xa1.z, w6, a0); c0 = fmaf(xa1.w, w7, c0);
    a1 = fmaf(xb0.x, w0, a1); c1 = fmaf(xb0.y, w1, c1);
    a1 = fmaf(xb0.z, w2, a1); c1 = fmaf(xb0.w, w3, c1);
    a1 = fmaf(xb1.x, w4, a1); c1 = fmaf(xb1.y, w5, c1);
    a1 = fmaf(xb1.z, w6, a1); c1 = fmaf(xb1.w, w7, c1);
  }
  a0 += c0 + bias[j];
  a1 += c1 + bias[j];
  hraw[rowA * NEUR + j] = a0;
  hraw[rowB * NEUR + j] = a1;
  __syncthreads();

  // LayerNorm stats: wave w reduces row w (64 lanes x 2 elems)
  {
    const float v1 = hraw[wrow * NEUR + lane];
    const float v2 = hraw[wrow * NEUR + lane + 64];
    float s = v1 + v2, q = v1 * v1 + v2 * v2;
#pragma unroll
    for (int m = 32; m; m >>= 1) {
      s += __shfl_xor(s, m, 64);
      q += __shfl_xor(q, m, 64);
    }
    if (lane == 0) {
      const float mu = s * (1.f / 128.f);
      const float var = q * (1.f / 128.f) - mu * mu;
      mu_s[wrow] = mu;
      rs_s[wrow] = rsqrtf(var + 1e-5f);
    }
  }
  __syncthreads();

  {
    const float vA = (a0 - mu_s[rowA]) * rs_s[rowA] * gain[j] + beta[j];
    const float vB = (a1 - mu_s[rowB]) * rs_s[rowB] * gain[j] + beta[j];
    hact[rowA * NEUR + j] = tanh_fast(vA);
    hact[rowB * NEUR + j] = tanh_fast(vB);
  }
  __syncthreads();
}

__global__ __launch_bounds__(256, 1)
void latent_ode_kernel(const float* __restrict__ z0,
                       const float* __restrict__ tt,
                       const float* __restrict__ cond,
                       const float* __restrict__ W0, const float* __restrict__ b0,
                       const float* __restrict__ g0, const float* __restrict__ be0,
                       const float* __restrict__ W1, const float* __restrict__ b1,
                       const float* __restrict__ g1, const float* __restrict__ be1,
                       const float* __restrict__ W2, const float* __restrict__ b2,
                       const float* __restrict__ g2, const float* __restrict__ be2,
                       const float* __restrict__ Wo, const float* __restrict__ bo,
                       float* __restrict__ out)
{
  __shared__ __align__(16) unsigned short w0t[NEUR * SP0];
  __shared__ __align__(16) unsigned short w1t[NEUR * SP1];
  __shared__ __align__(16) unsigned short w2t[NEUR * SP1];
  __shared__ __align__(16) unsigned short wot[LATENT * SP1];
  __shared__ __align__(16) float xin4[ROWS * DIN0];   // [row][0:64]=z, [64:160]=cond
  __shared__ __align__(16) float hraw[ROWS * NEUR];
  __shared__ __align__(16) float hact[ROWS * NEUR];
  __shared__ float bb0[NEUR], gg0[NEUR], bt0[NEUR];
  __shared__ float bb1[NEUR], gg1[NEUR], bt1[NEUR];
  __shared__ float bb2[NEUR], gg2[NEUR], bt2[NEUR];
  __shared__ float bbo[LATENT];
  __shared__ float mu_s[ROWS], rs_s[ROWS], dt_s[ROWS];

  const int t = threadIdx.x;
  const int r0 = blockIdx.x * ROWS;

  // ---- stage weights (bf16, transposed [neuron][k]) into LDS
  for (int idx = t; idx < DIN0 * NEUR; idx += 256) {
    const int k = idx >> 7, jj = idx & (NEUR - 1);
    w0t[jj * SP0 + k] = f2bf(W0[idx]);
  }
  for (int idx = t; idx < NEUR * NEUR; idx += 256) {
    const int k = idx >> 7, jj = idx & (NEUR - 1);
    w1t[jj * SP1 + k] = f2bf(W1[idx]);
    w2t[jj * SP1 + k] = f2bf(W2[idx]);
  }
  for (int idx = t; idx < NEUR * LATENT; idx += 256) {
    const int k = idx >> 6, jj = idx & (LATENT - 1);
    wot[jj * SP1 + k] = f2bf(Wo[idx]);
  }
  for (int idx = t; idx < NEUR; idx += 256) {
    bb0[idx] = b0[idx]; gg0[idx] = g0[idx]; bt0[idx] = be0[idx];
    bb1[idx] = b1[idx]; gg1[idx] = g1[idx]; bt1[idx] = be1[idx];
    bb2[idx] = b2[idx]; gg2[idx] = g2[idx]; bt2[idx] = be2[idx];
  }
  if (t < LATENT) bbo[t] = bo[t];

  // ---- init z and write trajectory step 0
  {
    const int row = t >> 6, jj = t & 63;
    const float z = z0[(size_t)(r0 + row) * LATENT + jj];
    xin4[row * DIN0 + jj] = z;
    out[((size_t)(r0 + row) * NSEQ) * LATENT + jj] = z;
  }
  __syncthreads();

  for (int i = 0; i < NSEQ - 1; ++i) {
    // load cond_i for 4 rows, and dt
    for (int idx = t; idx < ROWS * CONDD; idx += 256) {
      const int row = idx / CONDD;
      const int c = idx - row * CONDD;
      xin4[row * DIN0 + LATENT + c] =
          cond[((size_t)(r0 + row) * NSEQ + i) * CONDD + c];
    }
    if (t < ROWS) {
      const float* tp = tt + (size_t)(r0 + t) * NSEQ;
      dt_s[t] = tp[i + 1] - tp[i];
    }
    __syncthreads();

    layer_fwd<DIN0>(w0t, SP0, xin4, DIN0, hraw, hact, bb0, gg0, bt0, mu_s, rs_s, t);
    layer_fwd<NEUR>(w1t, SP1, hact, NEUR, hraw, hact, bb1, gg1, bt1, mu_s, rs_s, t);
    layer_fwd<NEUR>(w2t, SP1, hact, NEUR, hraw, hact, bb2, gg2, bt2, mu_s, rs_s, t);

    // ---- output layer: dz = hact @ Wo + bo; z += dt*dz
    {
      const int jo = t & 63, row = t >> 6;
      const unsigned short* wr = wot + jo * SP1;
      const float* xr = hact + row * NEUR;
      float a = 0.f, c = 0.f;
#pragma unroll 4
      for (int k = 0; k < NEUR; k += 8) {
        const uint4 wq = *(const uint4*)(wr + k);
        const float4 x0 = *(const float4*)(xr + k);
        const float4 x1 = *(const float4*)(xr + k + 4);
        a = fmaf(x0.x, lo16(wq.x), a); c = fmaf(x0.y, hi16(wq.x), c);
        a = fmaf(x0.z, lo16(wq.y), a); c = fmaf(x0.w, hi16(wq.y), c);
        a = fmaf(x1.x, lo16(wq.z), a); c = fmaf(x1.y, hi16(wq.z), c);
        a = fmaf(x1.z, lo16(wq.w), a); c = fmaf(x1.w, hi16(wq.w), c);
      }
      const float dz = a + c + bbo[jo];
      const float znew = xin4[row * DIN0 + jo] + dt_s[row] * dz;
      xin4[row * DIN0 + jo] = znew;
      out[((size_t)(r0 + row) * NSEQ + (i + 1)) * LATENT + jo] = znew;
    }
    __syncthreads();
  }
}

extern "C" void kernel_launch(void* const* d_in, const int* in_sizes, int n_in,
                              void* d_out, int out_size, void* d_ws, size_t ws_size,
                              hipStream_t stream) {
  const float* z0   = (const float*)d_in[0];
  const float* tt   = (const float*)d_in[1];
  const float* cond = (const float*)d_in[2];
  const float* W0   = (const float*)d_in[3];
  const float* b0   = (const float*)d_in[4];
  const float* g0   = (const float*)d_in[5];
  const float* be0  = (const float*)d_in[6];
  const float* W1   = (const float*)d_in[7];
  const float* b1   = (const float*)d_in[8];
  const float* g1   = (const float*)d_in[9];
  const float* be1  = (const float*)d_in[10];
  const float* W2   = (const float*)d_in[11];
  const float* b2   = (const float*)d_in[12];
  const float* g2   = (const float*)d_in[13];
  const float* be2  = (const float*)d_in[14];
  const float* Wo   = (const float*)d_in[15];
  const float* bo   = (const float*)d_in[16];
  float* out = (float*)d_out;

  hipLaunchKernelGGL(latent_ode_kernel, dim3(256), dim3(256), 0, stream,
                     z0, tt, cond, W0, b0, g0, be0, W1, b1, g1, be1,
                     W2, b2, g2, be2, Wo, bo, out);
}

// Round 2
// 2876.674 us; speedup vs baseline: 1.5902x; 1.5902x over previous
//
#include <hip/hip_runtime.h>
#include <stdint.h>

#define NSEQ 512
#define XS 168   // xin row stride (bf16 elems): 84 dw -> banks spread, 2-way max
#define AS 136   // act row stride: 68 dw -> 2-way max
#define ZS 68    // z32 row stride (f32)
#define TTS 516  // tts row stride (f32)

typedef short bfrag __attribute__((ext_vector_type(8)));
typedef float f4 __attribute__((ext_vector_type(4)));

__device__ __forceinline__ float bf2f(unsigned short u){
  return __uint_as_float(((uint32_t)u) << 16);
}
__device__ __forceinline__ unsigned short f2bf(float f){
  uint32_t u = __float_as_uint(f);
  u += 0x7FFFu + ((u >> 16) & 1u);   // RNE
  return (unsigned short)(u >> 16);
}
__device__ __forceinline__ float tanh_fast(float v){
  float e = __expf(2.f * v);
  return 1.f - __fdividef(2.f, e + 1.f);
}
__device__ __forceinline__ bfrag zero_frag(){
  bfrag z = {0,0,0,0,0,0,0,0};
  return z;
}
// B-fragment for mfma_f32_16x16x32_bf16: lane holds W[k0+j][col], j=0..7
__device__ __forceinline__ bfrag load_bfrag(const float* __restrict__ W, int N, int col, int k0){
  union { bfrag v; unsigned short u[8]; } r;
#pragma unroll
  for (int j = 0; j < 8; ++j) r.u[j] = f2bf(W[(size_t)(k0 + j) * N + col]);
  return r.v;
}

// h = tanh(LN(x@W + b)*g + beta). A is hi/lo bf16 split (fp32-accurate).
// Wave w owns cols 16w..16w+15. C layout: row=(lane>>4)*4+reg, col=lane&15.
template<int NKT>
__device__ __forceinline__ void hidden_layer(
    const unsigned short* hbuf, const unsigned short* lbuf, const int istride,
    const bfrag* Bw, const float bias_r, const float gain_r, const float beta_r,
    unsigned short* oh, unsigned short* ol,
    float* part_s, float* part_q,
    const int w, const int l, const int lg, const int lc, const int colw)
{
  const int aoff = lc * istride + lg * 8;
  bfrag ah[NKT], al[NKT];
#pragma unroll
  for (int kt = 0; kt < NKT; ++kt){
    ah[kt] = *(const bfrag*)(hbuf + aoff + kt * 32);
    al[kt] = *(const bfrag*)(lbuf + aoff + kt * 32);
  }
  f4 acc1 = {0,0,0,0}, acc2 = {0,0,0,0};
#pragma unroll
  for (int kt = 0; kt < NKT; ++kt){
    acc1 = __builtin_amdgcn_mfma_f32_16x16x32_bf16(ah[kt], Bw[kt], acc1, 0, 0, 0);
    acc2 = __builtin_amdgcn_mfma_f32_16x16x32_bf16(al[kt], Bw[kt], acc2, 0, 0, 0);
  }
  float h[4], s[4], q[4];
#pragma unroll
  for (int g = 0; g < 4; ++g){
    h[g] = (acc1[g] + acc2[g]) + bias_r;
    s[g] = h[g];
    q[g] = h[g] * h[g];
  }
  // col-reduce within each 16-lane row-group (rows lg*4+g)
#pragma unroll
  for (int m = 1; m < 16; m <<= 1){
#pragma unroll
    for (int g = 0; g < 4; ++g){
      s[g] += __shfl_xor(s[g], m, 64);
      q[g] += __shfl_xor(q[g], m, 64);
    }
  }
  if (lc == 0){
#pragma unroll
    for (int g = 0; g < 4; ++g){
      part_s[(lg*4 + g)*8 + w] = s[g];
      part_q[(lg*4 + g)*8 + w] = q[g];
    }
  }
  __syncthreads();
  // redundant cross-wave reduce: lane handles row R, broadcast via shfl
  const int R = lg*4 + (lc & 3);
  f4 p0 = *(const f4*)(part_s + R*8);
  f4 p1 = *(const f4*)(part_s + R*8 + 4);
  f4 u0 = *(const f4*)(part_q + R*8);
  f4 u1 = *(const f4*)(part_q + R*8 + 4);
  float ss = ((p0.x+p0.y)+(p0.z+p0.w)) + ((p1.x+p1.y)+(p1.z+p1.w));
  float qq = ((u0.x+u0.y)+(u0.z+u0.w)) + ((u1.x+u1.y)+(u1.z+u1.w));
  float mu = ss * 0.0078125f;
  float var = qq * 0.0078125f - mu * mu;
  float rs = rsqrtf(var + 1e-5f);
#pragma unroll
  for (int g = 0; g < 4; ++g){
    float mug = __shfl(mu, (l & 48) | g, 64);
    float rsg = __shfl(rs, (l & 48) | g, 64);
    float v = (h[g] - mug) * rsg * gain_r + beta_r;
    float a = tanh_fast(v);
    unsigned short hh = f2bf(a);
    oh[(lg*4 + g)*AS + colw] = hh;
    ol[(lg*4 + g)*AS + colw] = f2bf(a - bf2f(hh));
  }
  __syncthreads();
}

__global__ __launch_bounds__(512, 2)
void latent_ode_mfma(const float* __restrict__ z0, const float* __restrict__ tt,
                     const float* __restrict__ cond,
                     const float* __restrict__ W0, const float* __restrict__ b0,
                     const float* __restrict__ g0, const float* __restrict__ be0,
                     const float* __restrict__ W1, const float* __restrict__ b1,
                     const float* __restrict__ g1, const float* __restrict__ be1,
                     const float* __restrict__ W2, const float* __restrict__ b2,
                     const float* __restrict__ g2, const float* __restrict__ be2,
                     const float* __restrict__ Wo, const float* __restrict__ bo,
                     float* __restrict__ out)
{
  __shared__ __align__(16) unsigned short xin_bf[16*XS];
  __shared__ __align__(16) unsigned short xin_lo[16*XS];
  __shared__ __align__(16) unsigned short act_bf[16*AS];
  __shared__ __align__(16) unsigned short act_lo[16*AS];
  __shared__ __align__(16) float z32[16*ZS];
  __shared__ __align__(16) float tts[16*TTS];
  __shared__ __align__(16) float part_s[16*8];
  __shared__ __align__(16) float part_q[16*8];

  const int t  = threadIdx.x;
  const int w  = t >> 6;
  const int l  = t & 63;
  const int lg = l >> 4;
  const int lc = l & 15;
  const int cw = w*16 + lc;          // this wave's output col (hidden layers)
  const int r0 = blockIdx.x * 16;
  const int k0l = lg * 8;

  // ---- weights -> per-wave B-fragments in registers (one-time)
  bfrag B0w[5], B1w[4], B2w[4], Bo0[4], Bo1[4];
#pragma unroll
  for (int kt = 0; kt < 5; ++kt) B0w[kt] = load_bfrag(W0, 128, cw, kt*32 + k0l);
#pragma unroll
  for (int kt = 0; kt < 4; ++kt) B1w[kt] = load_bfrag(W1, 128, cw, kt*32 + k0l);
#pragma unroll
  for (int kt = 0; kt < 4; ++kt) B2w[kt] = load_bfrag(W2, 128, cw, kt*32 + k0l);
  float bo_r0 = 0.f, bo_r1 = 0.f;
  if (w < 2){
#pragma unroll
    for (int kt = 0; kt < 4; ++kt){
      Bo0[kt] = load_bfrag(Wo, 64, (w*2 + 0)*16 + lc, kt*32 + k0l);
      Bo1[kt] = load_bfrag(Wo, 64, (w*2 + 1)*16 + lc, kt*32 + k0l);
    }
    bo_r0 = bo[(w*2 + 0)*16 + lc];
    bo_r1 = bo[(w*2 + 1)*16 + lc];
  } else {
#pragma unroll
    for (int kt = 0; kt < 4; ++kt){ Bo0[kt] = zero_frag(); Bo1[kt] = zero_frag(); }
  }
  const float b0_r = b0[cw], g0_r = g0[cw], be0_r = be0[cw];
  const float b1_r = b1[cw], g1_r = g1[cw], be1_r = be1[cw];
  const float b2_r = b2[cw], g2_r = g2[cw], be2_r = be2[cw];

  // ---- stage full time grid (removes per-step global dependency)
#pragma unroll
  for (int r = 0; r < 16; ++r) tts[r*TTS + t] = tt[(size_t)(r0 + r)*NSEQ + t];

  // ---- z init (fp32 state + hi/lo bf16 copy) + out step 0
  {
    const int zr = t >> 5;
    const int zc = (t & 31) * 2;
    float2 zv = *(const float2*)(z0 + (size_t)(r0 + zr)*64 + zc);
    z32[zr*ZS + zc]     = zv.x;
    z32[zr*ZS + zc + 1] = zv.y;
    unsigned short h0 = f2bf(zv.x), h1 = f2bf(zv.y);
    xin_bf[zr*XS + zc]     = h0;  xin_lo[zr*XS + zc]     = f2bf(zv.x - bf2f(h0));
    xin_bf[zr*XS + zc + 1] = h1;  xin_lo[zr*XS + zc + 1] = f2bf(zv.y - bf2f(h1));
    *(float2*)(out + ((size_t)(r0 + zr)*NSEQ)*64 + zc) = zv;
  }

  // ---- cond prefetch pipeline (waves 2-7: 384 threads x float4 = 16 rows x 96)
  const bool stg = (t >= 128);
  int sr = 0, sq = 0;
  if (stg){ int c = t - 128; sr = c / 24; sq = c - sr*24; }
  float4 pf = {0.f, 0.f, 0.f, 0.f};
  if (stg) pf = *(const float4*)(cond + ((size_t)(r0 + sr)*NSEQ + 0)*96 + sq*4);

  __syncthreads();

  for (int i = 0; i < NSEQ - 1; ++i){
    // write cond(i) hi/lo to xin; issue load of cond(i+1) (hides under step i)
    if (stg){
      unsigned short h0 = f2bf(pf.x), h1 = f2bf(pf.y), h2 = f2bf(pf.z), h3 = f2bf(pf.w);
      unsigned short q0 = f2bf(pf.x - bf2f(h0)), q1 = f2bf(pf.y - bf2f(h1));
      unsigned short q2 = f2bf(pf.z - bf2f(h2)), q3 = f2bf(pf.w - bf2f(h3));
      uint2 ph, pl;
      ph.x = (uint32_t)h0 | ((uint32_t)h1 << 16);
      ph.y = (uint32_t)h2 | ((uint32_t)h3 << 16);
      pl.x = (uint32_t)q0 | ((uint32_t)q1 << 16);
      pl.y = (uint32_t)q2 | ((uint32_t)q3 << 16);
      *(uint2*)(xin_bf + sr*XS + 64 + sq*4) = ph;
      *(uint2*)(xin_lo + sr*XS + 64 + sq*4) = pl;
      if (i < NSEQ - 2)
        pf = *(const float4*)(cond + ((size_t)(r0 + sr)*NSEQ + (i + 1))*96 + sq*4);
    }
    __syncthreads();   // xin (z from prev step, cond for this step) ready

    hidden_layer<5>(xin_bf, xin_lo, XS, B0w, b0_r, g0_r, be0_r,
                    act_bf, act_lo, part_s, part_q, w, l, lg, lc, cw);
    hidden_layer<4>(act_bf, act_lo, AS, B1w, b1_r, g1_r, be1_r,
                    act_bf, act_lo, part_s, part_q, w, l, lg, lc, cw);
    hidden_layer<4>(act_bf, act_lo, AS, B2w, b2_r, g2_r, be2_r,
                    act_bf, act_lo, part_s, part_q, w, l, lg, lc, cw);

    // output layer + Euler update on waves 0-1 (overlaps next step's cond staging)
    if (w < 2){
      bfrag ah[4], al[4];
#pragma unroll
      for (int kt = 0; kt < 4; ++kt){
        ah[kt] = *(const bfrag*)(act_bf + lc*AS + kt*32 + k0l);
        al[kt] = *(const bfrag*)(act_lo + lc*AS + kt*32 + k0l);
      }
      float dtv[4];
#pragma unroll
      for (int g = 0; g < 4; ++g){
        int row = lg*4 + g;
        dtv[g] = tts[row*TTS + i + 1] - tts[row*TTS + i];
      }
      f4 a1 = {0,0,0,0}, a2 = {0,0,0,0}, a3 = {0,0,0,0}, a4 = {0,0,0,0};
#pragma unroll
      for (int kt = 0; kt < 4; ++kt){
        a1 = __builtin_amdgcn_mfma_f32_16x16x32_bf16(ah[kt], Bo0[kt], a1, 0, 0, 0);
        a2 = __builtin_amdgcn_mfma_f32_16x16x32_bf16(al[kt], Bo0[kt], a2, 0, 0, 0);
        a3 = __builtin_amdgcn_mfma_f32_16x16x32_bf16(ah[kt], Bo1[kt], a3, 0, 0, 0);
        a4 = __builtin_amdgcn_mfma_f32_16x16x32_bf16(al[kt], Bo1[kt], a4, 0, 0, 0);
      }
      const int colo0 = (w*2)*16 + lc, colo1 = colo0 + 16;
#pragma unroll
      for (int g = 0; g < 4; ++g){
        int row = lg*4 + g;
        float dz0 = (a1[g] + a2[g]) + bo_r0;
        float dz1 = (a3[g] + a4[g]) + bo_r1;
        float zn0 = z32[row*ZS + colo0] + dtv[g]*dz0;
        float zn1 = z32[row*ZS + colo1] + dtv[g]*dz1;
        z32[row*ZS + colo0] = zn0;
        z32[row*ZS + colo1] = zn1;
        unsigned short hh0 = f2bf(zn0), hh1 = f2bf(zn1);
        xin_bf[row*XS + colo0] = hh0; xin_lo[row*XS + colo0] = f2bf(zn0 - bf2f(hh0));
        xin_bf[row*XS + colo1] = hh1; xin_lo[row*XS + colo1] = f2bf(zn1 - bf2f(hh1));
        size_t ob = ((size_t)(r0 + row)*NSEQ + (size_t)(i + 1))*64;
        out[ob + colo0] = zn0;
        out[ob + colo1] = zn1;
      }
    }
    // no barrier here: staging (waves 2-7) writes xin cond region, Lo (waves 0-1)
    // writes xin z region / act reads — disjoint; next loop-top barrier orders all.
  }
}

extern "C" void kernel_launch(void* const* d_in, const int* in_sizes, int n_in,
                              void* d_out, int out_size, void* d_ws, size_t ws_size,
                              hipStream_t stream) {
  const float* z0   = (const float*)d_in[0];
  const float* tt   = (const float*)d_in[1];
  const float* cond = (const float*)d_in[2];
  const float* W0   = (const float*)d_in[3];
  const float* b0   = (const float*)d_in[4];
  const float* g0   = (const float*)d_in[5];
  const float* be0  = (const float*)d_in[6];
  const float* W1   = (const float*)d_in[7];
  const float* b1   = (const float*)d_in[8];
  const float* g1   = (const float*)d_in[9];
  const float* be1  = (const float*)d_in[10];
  const float* W2   = (const float*)d_in[11];
  const float* b2   = (const float*)d_in[12];
  const float* g2   = (const float*)d_in[13];
  const float* be2  = (const float*)d_in[14];
  const float* Wo   = (const float*)d_in[15];
  const float* bo   = (const float*)d_in[16];
  float* out = (float*)d_out;

  hipLaunchKernelGGL(latent_ode_mfma, dim3(64), dim3(512), 0, stream,
                     z0, tt, cond, W0, b0, g0, be0, W1, b1, g1, be1,
                     W2, b2, g2, be2, Wo, bo, out);
}

// Round 3
// 2084.563 us; speedup vs baseline: 2.1944x; 1.3800x over previous
//
#include <hip/hip_runtime.h>
#include <stdint.h>

#define NSEQ 512
#define XS 328   // xin row stride (shorts): 656B = 41 x 16B groups (odd -> spread)
#define AS 136   // act row stride (shorts): 272B = 17 x 16B groups (odd)
#define TS 516   // dts row stride (f32): 516%32=4 -> 2-way max on strided row reads
#define EPS 1e-5f

typedef short bfrag __attribute__((ext_vector_type(8)));
typedef float f4 __attribute__((ext_vector_type(4)));

__device__ __forceinline__ float bf2f(unsigned short u){ return __uint_as_float(((uint32_t)u)<<16); }
__device__ __forceinline__ unsigned short f2bf(float f){
  uint32_t u = __float_as_uint(f);
  u += 0x7FFFu + ((u>>16)&1u);   // RNE
  return (unsigned short)(u>>16);
}
__device__ __forceinline__ float tanh_fast(float v){
  float e = __expf(2.f*v);
  return 1.f - __fdividef(2.f, e+1.f);
}

// One hidden layer for 16 rows. Wave w owns cols [32w, 32w+32).
// A: lane holds row=lc, k=lg*8+j (+32*kt). C: col=lc (+16*nt), row=4*lg+g.
template<int NKT>
__device__ __forceinline__ void mlp_layer(
    const unsigned short* __restrict__ inb, const int istride,
    const bfrag (&B)[2][NKT],
    const float (&br)[2], const float (&gr)[2], const float (&ber)[2],
    unsigned short* __restrict__ actb, float* __restrict__ part,
    const int w, const int lg, const int lc)
{
  const int aoff = lc*istride + lg*8;
  bfrag a[NKT];
#pragma unroll
  for (int kt=0; kt<NKT; ++kt) a[kt] = *(const bfrag*)(inb + aoff + kt*32);
  f4 acc0 = {0,0,0,0}, acc1 = {0,0,0,0};
#pragma unroll
  for (int kt=0; kt<NKT; ++kt){
    acc0 = __builtin_amdgcn_mfma_f32_16x16x32_bf16(a[kt], B[0][kt], acc0, 0,0,0);
    acc1 = __builtin_amdgcn_mfma_f32_16x16x32_bf16(a[kt], B[1][kt], acc1, 0,0,0);
  }
  float h0[4], h1[4], s[4], q[4];
#pragma unroll
  for (int g=0; g<4; ++g){
    h0[g] = acc0[g] + br[0];
    h1[g] = acc1[g] + br[1];
    s[g] = h0[g] + h1[g];
    q[g] = h0[g]*h0[g] + h1[g]*h1[g];
  }
#pragma unroll
  for (int m=1; m<16; m<<=1){
#pragma unroll
    for (int g=0; g<4; ++g){
      s[g] += __shfl_xor(s[g], m, 64);
      q[g] += __shfl_xor(q[g], m, 64);
    }
  }
  if (lc == 0){
#pragma unroll
    for (int g=0; g<4; ++g)
      *(float2*)(part + (lg*4+g)*8 + w*2) = make_float2(s[g], q[g]);
  }
  __syncthreads();   // B1: partials visible
  float mu[4], rs[4];
#pragma unroll
  for (int g=0; g<4; ++g){
    const int row = lg*4 + g;
    f4 p0 = *(const f4*)(part + row*8);
    f4 p1 = *(const f4*)(part + row*8 + 4);
    float ss = (p0.x + p0.z) + (p1.x + p1.z);
    float qq = (p0.y + p0.w) + (p1.y + p1.w);
    mu[g] = ss * 0.0078125f;
    float var = qq * 0.0078125f - mu[g]*mu[g];
    rs[g] = rsqrtf(var + EPS);
  }
  const int c0 = w*32 + lc;
#pragma unroll
  for (int g=0; g<4; ++g){
    const int row = lg*4 + g;
    float v0 = (h0[g]-mu[g])*rs[g]*gr[0] + ber[0];
    float v1 = (h1[g]-mu[g])*rs[g]*gr[1] + ber[1];
    actb[row*AS + c0]      = f2bf(tanh_fast(v0));
    actb[row*AS + c0 + 16] = f2bf(tanh_fast(v1));
  }
  __syncthreads();   // B2: act complete
}

__global__ __launch_bounds__(256, 1)
void latent_ode_v3(const float* __restrict__ z0, const float* __restrict__ tt,
                   const float* __restrict__ cond,
                   const float* __restrict__ W0, const float* __restrict__ b0,
                   const float* __restrict__ g0, const float* __restrict__ be0,
                   const float* __restrict__ W1, const float* __restrict__ b1,
                   const float* __restrict__ g1, const float* __restrict__ be1,
                   const float* __restrict__ W2, const float* __restrict__ b2,
                   const float* __restrict__ g2, const float* __restrict__ be2,
                   const float* __restrict__ Wo, const float* __restrict__ bo,
                   float* __restrict__ out)
{
  // xin K layout: [0:64 z_hi][64:128 z_lo][128:224 cond_hi][224:320 cond_lo]
  __shared__ __align__(16) unsigned short xin[16*XS];
  __shared__ __align__(16) unsigned short act[16*AS];
  __shared__ __align__(16) float dts[16*TS];
  __shared__ __align__(16) float part[16*8];

  const int t  = threadIdx.x;
  const int w  = t >> 6;
  const int l  = t & 63;
  const int lg = l >> 4;
  const int lc = l & 15;
  const int r0 = blockIdx.x * 16;
  const int colo = w*16 + lc;   // output-layer col owned by this lane

  // ---- weights -> VGPR B-fragments (one-time)
  bfrag B0f[2][10], B1f[2][4], B2f[2][4], Bof[4];
#pragma unroll
  for (int nt=0; nt<2; ++nt){
    const int col = w*32 + nt*16 + lc;
#pragma unroll
    for (int kt=0; kt<10; ++kt){
      union { bfrag v; unsigned short u[8]; } r;
#pragma unroll
      for (int j=0; j<8; ++j){
        const int k = kt*32 + lg*8 + j;
        const int src = (k<64) ? k : (k<128) ? (k-64) : (k<224) ? (64 + k-128) : (64 + k-224);
        r.u[j] = f2bf(W0[(size_t)src*128 + col]);
      }
      B0f[nt][kt] = r.v;
    }
#pragma unroll
    for (int kt=0; kt<4; ++kt){
      union { bfrag v; unsigned short u[8]; } r1, r2;
#pragma unroll
      for (int j=0; j<8; ++j){
        const int k = kt*32 + lg*8 + j;
        r1.u[j] = f2bf(W1[(size_t)k*128 + col]);
        r2.u[j] = f2bf(W2[(size_t)k*128 + col]);
      }
      B1f[nt][kt] = r1.v; B2f[nt][kt] = r2.v;
    }
  }
#pragma unroll
  for (int kt=0; kt<4; ++kt){
    union { bfrag v; unsigned short u[8]; } r;
#pragma unroll
    for (int j=0; j<8; ++j){
      const int k = kt*32 + lg*8 + j;
      r.u[j] = f2bf(Wo[(size_t)k*64 + colo]);
    }
    Bof[kt] = r.v;
  }
  float br0[2],gr0[2],ber0[2], br1[2],gr1[2],ber1[2], br2[2],gr2[2],ber2[2];
#pragma unroll
  for (int nt=0; nt<2; ++nt){
    const int col = w*32 + nt*16 + lc;
    br0[nt]=b0[col]; gr0[nt]=g0[col]; ber0[nt]=be0[col];
    br1[nt]=b1[col]; gr1[nt]=g1[col]; ber1[nt]=be1[col];
    br2[nt]=b2[col]; gr2[nt]=g2[col]; ber2[nt]=be2[col];
  }
  const float bor = bo[colo];

  // ---- dt table
  {
    const int row = t >> 4, j0 = t & 15;
    const float* tp = tt + (size_t)(r0+row)*NSEQ;
    for (int j=j0; j<NSEQ-1; j+=16)
      dts[row*TS + j] = tp[j+1] - tp[j];
  }

  // ---- z state in VGPRs (rows 4*lg+g, col colo) + xin z init + out step 0
  float zr[4];
#pragma unroll
  for (int g=0; g<4; ++g){
    const int row = lg*4 + g;
    const float z = z0[(size_t)(r0+row)*64 + colo];
    zr[g] = z;
    const unsigned short h = f2bf(z);
    xin[row*XS + colo]      = h;
    xin[row*XS + 64 + colo] = f2bf(z - bf2f(h));
    out[((size_t)(r0+row)*NSEQ)*64 + colo] = z;
  }

  // ---- cond: stage step 0 directly, prefetch step 1
  const int srow = t >> 4, sq = t & 15;   // 16 threads/row, float2 slots sq,sq+16,sq+32
  const float* cbase = cond + ((size_t)(r0+srow)*NSEQ)*96;
  float2 pf[3];
#pragma unroll
  for (int k2=0; k2<3; ++k2){
    const int s2 = (sq + 16*k2)*2;
    float2 c = *(const float2*)(cbase + s2);
    unsigned short h0 = f2bf(c.x), h1 = f2bf(c.y);
    *(uint32_t*)(xin + srow*XS + 128 + s2) = (uint32_t)h0 | ((uint32_t)h1 << 16);
    *(uint32_t*)(xin + srow*XS + 224 + s2) =
        (uint32_t)f2bf(c.x - bf2f(h0)) | ((uint32_t)f2bf(c.y - bf2f(h1)) << 16);
    pf[k2] = *(const float2*)(cbase + 96 + s2);
  }
  __syncthreads();

  for (int i=0; i<NSEQ-1; ++i){
    mlp_layer<10>(xin, XS, B0f, br0, gr0, ber0, act, part, w, lg, lc);
    mlp_layer<4> (act, AS, B1f, br1, gr1, ber1, act, part, w, lg, lc);
    mlp_layer<4> (act, AS, B2f, br2, gr2, ber2, act, part, w, lg, lc);

    // ---- output layer + Euler update (all waves symmetric: 16 cols each)
    {
      const int aoff = lc*AS + lg*8;
      bfrag a[4];
#pragma unroll
      for (int kt=0; kt<4; ++kt) a[kt] = *(const bfrag*)(act + aoff + kt*32);
      f4 ao = {0,0,0,0};
#pragma unroll
      for (int kt=0; kt<4; ++kt)
        ao = __builtin_amdgcn_mfma_f32_16x16x32_bf16(a[kt], Bof[kt], ao, 0,0,0);
#pragma unroll
      for (int g=0; g<4; ++g){
        const int row = lg*4 + g;
        const float dt = dts[row*TS + i];
        const float zn = zr[g] + dt*(ao[g] + bor);
        zr[g] = zn;
        const unsigned short h = f2bf(zn);
        xin[row*XS + colo]      = h;
        xin[row*XS + 64 + colo] = f2bf(zn - bf2f(h));
        out[((size_t)(r0+row)*NSEQ + (size_t)(i+1))*64 + colo] = zn;
      }
    }

    // ---- stage cond(i+1) from prefetch regs; issue load of cond(i+2)
#pragma unroll
    for (int k2=0; k2<3; ++k2){
      const int s2 = (sq + 16*k2)*2;
      unsigned short h0 = f2bf(pf[k2].x), h1 = f2bf(pf[k2].y);
      *(uint32_t*)(xin + srow*XS + 128 + s2) = (uint32_t)h0 | ((uint32_t)h1 << 16);
      *(uint32_t*)(xin + srow*XS + 224 + s2) =
          (uint32_t)f2bf(pf[k2].x - bf2f(h0)) | ((uint32_t)f2bf(pf[k2].y - bf2f(h1)) << 16);
    }
    if (i < NSEQ-2){
#pragma unroll
      for (int k2=0; k2<3; ++k2)
        pf[k2] = *(const float2*)(cbase + (size_t)(i+2)*96 + (sq + 16*k2)*2);
    }
    __syncthreads();   // xin (z + cond for step i+1) ready
  }
}

extern "C" void kernel_launch(void* const* d_in, const int* in_sizes, int n_in,
                              void* d_out, int out_size, void* d_ws, size_t ws_size,
                              hipStream_t stream) {
  const float* z0   = (const float*)d_in[0];
  const float* tt   = (const float*)d_in[1];
  const float* cond = (const float*)d_in[2];
  const float* W0   = (const float*)d_in[3];
  const float* b0   = (const float*)d_in[4];
  const float* g0   = (const float*)d_in[5];
  const float* be0  = (const float*)d_in[6];
  const float* W1   = (const float*)d_in[7];
  const float* b1   = (const float*)d_in[8];
  const float* g1   = (const float*)d_in[9];
  const float* be1  = (const float*)d_in[10];
  const float* W2   = (const float*)d_in[11];
  const float* b2   = (const float*)d_in[12];
  const float* g2   = (const float*)d_in[13];
  const float* be2  = (const float*)d_in[14];
  const float* Wo   = (const float*)d_in[15];
  const float* bo   = (const float*)d_in[16];
  float* out = (float*)d_out;

  hipLaunchKernelGGL(latent_ode_v3, dim3(64), dim3(256), 0, stream,
                     z0, tt, cond, W0, b0, g0, be0, W1, b1, g1, be1,
                     W2, b2, g2, be2, Wo, bo, out);
}